// Round 1
// 150.971 us; speedup vs baseline: 1.0558x; 1.0558x over previous
//
#include <hip/hip_runtime.h>

// SegmentTree scatter-update + path propagation.
// capacity C = 2^23, n_updates = 2^20, tree = 2C floats (64 MiB).
//
// R8: single-pass binning. Previous version used coarse(256 bins) + fine(16
// sub-bins) = two latency-bound passes at 1 block/CU (est. 60-70 us combined
// for ~5 us of pure BW). This version bins directly into the 4096 fine bins
// in ONE pass: per-block LDS histogram over 4096 counters, one global
// atomicAdd reserve per non-empty (block,bin) (~2600/block, preserves 128 B
// contiguous write runs), LDS-cursor scatter into fbins. Merge/tail unchanged.
//
// Pipeline:
//   clear:  zero 4096 bin counters.
//   bin:    256 blocks x 1024 thr: int4/float4 loads, LDS hist -> global
//           reserve -> scatter into fbins (bin = idx >> 11, 512-entry cap).
//   merge:  block = 2048-leaf subtree: LDS-scatter fine bin, select vs tree
//           leaves, L1..L3 in registers, L4..L9 wave shuffles, L10/L11 thread0.
//   tail:   one block: L12/L13 in registers, M=512..16 wave shuffles,
//           1 barrier, wave 0 does M=8..1; out[0] = tree[0].
// Exact same pairwise sums as reference -> absmax 0.
//
// ws layout:
//   fcnt  uint[4096]       @ 0       (16 KB)
//   l11   uchar[4096]      @ 16384   (4 KB)
//   fbins uint2[4096*512]  @ 32768   (16 MB)

typedef unsigned int uint;
typedef unsigned char uchar;
typedef unsigned long long ull;

#define NBINS 4096
#define FCAP  512

// bit j of result = (c bit 2j) | (c bit 2j+1), 64-bit
__device__ __forceinline__ ull pc64(ull c) {
    ull x = (c | (c >> 1)) & 0x5555555555555555ull;
    x = (x | (x >> 1))  & 0x3333333333333333ull;
    x = (x | (x >> 2))  & 0x0F0F0F0F0F0F0F0Full;
    x = (x | (x >> 4))  & 0x00FF00FF00FF00FFull;
    x = (x | (x >> 8))  & 0x0000FFFF0000FFFFull;
    x = (x | (x >> 16)) & 0x00000000FFFFFFFFull;
    return x;
}

__global__ void clear_kernel(uint* __restrict__ fcnt) {
    fcnt[blockIdx.x * 256 + threadIdx.x] = 0u;
}

__global__ __launch_bounds__(1024)
void bin_kernel(const int* __restrict__ idx,
                const float* __restrict__ val,
                uint* __restrict__ fcnt,
                uint2* __restrict__ fbins) {
    __shared__ uint hist[NBINS];    // histogram, then reused as scatter cursor
    __shared__ uint rbase[NBINS];
    const int tid = threadIdx.x;

    #pragma unroll
    for (int e = 0; e < 4; ++e) hist[e * 1024 + tid] = 0u;
    __syncthreads();

    // 4096 updates/block, vectorized 16B loads.
    const int base4 = blockIdx.x * 1024 + tid;   // in int4 units
    int4   j4 = ((const int4*)idx)[base4];
    float4 v4 = ((const float4*)val)[base4];
    uint  j[4] = { (uint)j4.x, (uint)j4.y, (uint)j4.z, (uint)j4.w };
    float v[4] = { v4.x, v4.y, v4.z, v4.w };

    #pragma unroll
    for (int e = 0; e < 4; ++e) atomicAdd(&hist[j[e] >> 11], 1u);
    __syncthreads();

    // One global reserve per non-empty bin; zero cursor for reuse.
    #pragma unroll
    for (int e = 0; e < 4; ++e) {
        int bin = e * 1024 + tid;
        uint h = hist[bin];
        rbase[bin] = h ? atomicAdd(&fcnt[bin], h) : 0u;
        hist[bin] = 0u;
    }
    __syncthreads();

    // Scatter: contiguous run per (block,bin) -> coalescable 8B writes.
    #pragma unroll
    for (int e = 0; e < 4; ++e) {
        uint bin = j[e] >> 11;
        uint r = rbase[bin] + atomicAdd(&hist[bin], 1u);
        if (r < FCAP)
            fbins[((size_t)bin << 9) + r] =
                make_uint2(j[e] & 2047u, __float_as_uint(v[e]));
    }
}

__global__ __launch_bounds__(256)
void merge_kernel(const float* __restrict__ tree,
                  const uint* __restrict__ fcnt,
                  const uint2* __restrict__ fbins,
                  uchar* __restrict__ l11flag,
                  float* __restrict__ out, int C) {
    __shared__ float slv[2048];
    __shared__ uchar sfl[2048];
    __shared__ float swv[4];
    __shared__ uint  swd[4];

    const int b   = blockIdx.x;
    const int tid = threadIdx.x;
    const int w    = tid >> 6;
    const int lane = tid & 63;

    ((uint2*)sfl)[tid] = make_uint2(0u, 0u);
    __syncthreads();
    uint c = fcnt[b];
    if (c > FCAP) c = FCAP;
    const uint2* mybin = fbins + ((size_t)b << 9);
    for (uint k = tid; k < c; k += 256u) {
        uint2 e = mybin[k];
        uint off = e.x & 2047u;
        slv[off] = __uint_as_float(e.y);
        sfl[off] = 1;
    }
    __syncthreads();

    const int leaf0  = tid * 8;
    const int gleaf0 = b * 2048 + leaf0;

    uint2 fw = *(const uint2*)&sfl[leaf0];
    float4 la = *(const float4*)&slv[leaf0];
    float4 lb = *(const float4*)&slv[leaf0 + 4];
    float4 ta = *(const float4*)(tree + C + gleaf0);
    float4 tb = *(const float4*)(tree + C + gleaf0 + 4);

    float l0 = (fw.x & 0x000000FFu) ? la.x : ta.x;
    float l1 = (fw.x & 0x0000FF00u) ? la.y : ta.y;
    float l2 = (fw.x & 0x00FF0000u) ? la.z : ta.z;
    float l3 = (fw.x & 0xFF000000u) ? la.w : ta.w;
    float l4 = (fw.y & 0x000000FFu) ? lb.x : tb.x;
    float l5 = (fw.y & 0x0000FF00u) ? lb.y : tb.y;
    float l6 = (fw.y & 0x00FF0000u) ? lb.z : tb.z;
    float l7 = (fw.y & 0xFF000000u) ? lb.w : tb.w;

    *(float4*)(out + C + gleaf0)     = make_float4(l0, l1, l2, l3);
    *(float4*)(out + C + gleaf0 + 4) = make_float4(l4, l5, l6, l7);

    // ---- L1..L3 in registers ----
    uint d10 = (fw.x & 0x0000FFFFu) != 0u;
    uint d11 = (fw.x & 0xFFFF0000u) != 0u;
    uint d12 = (fw.y & 0x0000FFFFu) != 0u;
    uint d13 = (fw.y & 0xFFFF0000u) != 0u;
    float4 t1 = *(const float4*)(tree + (C >> 1) + (gleaf0 >> 1));
    float4 v1;
    v1.x = d10 ? l0 + l1 : t1.x;
    v1.y = d11 ? l2 + l3 : t1.y;
    v1.z = d12 ? l4 + l5 : t1.z;
    v1.w = d13 ? l6 + l7 : t1.w;
    *(float4*)(out + (C >> 1) + (gleaf0 >> 1)) = v1;

    float2 t2 = *(const float2*)(tree + (C >> 2) + (gleaf0 >> 2));
    uint d20 = d10 | d11, d21 = d12 | d13;
    float2 v2;
    v2.x = d20 ? v1.x + v1.y : t2.x;
    v2.y = d21 ? v1.z + v1.w : t2.y;
    *(float2*)(out + (C >> 2) + (gleaf0 >> 2)) = v2;

    float t3 = tree[(C >> 3) + (gleaf0 >> 3)];
    uint d3 = d20 | d21;
    float v = d3 ? v2.x + v2.y : t3;
    out[(C >> 3) + (gleaf0 >> 3)] = v;

    // ---- L4..L9: wave-shuffle reduction, no barriers ----
    ull m = __ballot(d3 != 0u);        // bit l = L3-dirty of lane l (uniform)
    #pragma unroll
    for (int lvl = 4; lvl <= 9; ++lvl) {
        float a  = __shfl(v, 2 * lane, 64);
        float bb = __shfl(v, 2 * lane + 1, 64);
        m = pc64(m);
        int n = 64 >> (lvl - 3);       // nodes per wave at this level
        if (lane < n) {
            int node = (C >> lvl) + ((b * 2048 + w * 512) >> lvl) + lane;
            uint d = (uint)(m >> lane) & 1u;
            v = d ? a + bb : tree[node];   // clean nodes carry tree value up
            out[node] = v;
        }
    }

    // ---- L10/L11: 4 wave results -> thread 0 ----
    if (lane == 0) { swv[w] = v; swd[w] = (uint)(m & 1ull); }
    __syncthreads();
    if (tid == 0) {
        uint da0 = swd[0] | swd[1], da1 = swd[2] | swd[3];
        int n10 = (C >> 10) + 2 * b;
        float v100 = da0 ? swv[0] + swv[1] : tree[n10];
        float v101 = da1 ? swv[2] + swv[3] : tree[n10 + 1];
        out[n10]     = v100;
        out[n10 + 1] = v101;
        uint d11f = da0 | da1;
        int n11 = (C >> 11) + b;
        out[n11] = d11f ? v100 + v101 : tree[n11];
        l11flag[b] = (uchar)d11f;
    }
}

// One block, 1024 threads: L12..L23 + out[0]. One barrier.
__global__ __launch_bounds__(1024)
void tail_kernel(const float* __restrict__ tree,
                 const uchar* __restrict__ l11flag,
                 float* __restrict__ out) {
    __shared__ float s16[16];
    __shared__ uint  sd16[16];
    const int t = threadIdx.x, w = t >> 6, lane = t & 63;

    // L12 (nodes [2048,4096)) + L13 (nodes [1024,2048)) in registers.
    float4 ch = *(const float4*)(out + 4096 + 4 * t);   // L11 values
    uint fl = ((const uint*)l11flag)[t];                // 4 dirty bytes
    uint d0 = (fl & 0x0000FFFFu) != 0u;
    uint d1 = (fl & 0xFFFF0000u) != 0u;
    float2 t12 = *(const float2*)(tree + 2048 + 2 * t);
    float v0 = d0 ? ch.x + ch.y : t12.x;
    float v1 = d1 ? ch.z + ch.w : t12.y;
    *(float2*)(out + 2048 + 2 * t) = make_float2(v0, v1);
    uint d = d0 | d1;
    float v = d ? v0 + v1 : tree[1024 + t];
    out[1024 + t] = v;

    // M = 512..16: wave shuffles (nodes/wave = M/16).
    ull m = __ballot(d != 0u);
    #pragma unroll
    for (int M = 512; M >= 16; M >>= 1) {
        float a  = __shfl(v, 2 * lane, 64);
        float bb = __shfl(v, 2 * lane + 1, 64);
        m = pc64(m);
        int nw = M >> 4;
        if (lane < nw) {
            int node = M + nw * w + lane;
            uint dd = (uint)(m >> lane) & 1u;
            v = dd ? a + bb : tree[node];
            out[node] = v;
        }
    }
    if (lane == 0) { s16[w] = v; sd16[w] = (uint)(m & 1ull); }
    __syncthreads();

    // Wave 0 finishes M = 8..1 from the 16 M=16 values.
    if (w == 0) {
        float vv = lane < 16 ? s16[lane] : 0.f;
        uint dd  = lane < 16 ? sd16[lane] : 0u;
        ull mm = __ballot(dd != 0u);
        #pragma unroll
        for (int M = 8; M >= 1; M >>= 1) {
            float a  = __shfl(vv, 2 * lane, 64);
            float bb = __shfl(vv, 2 * lane + 1, 64);
            mm = pc64(mm);
            if (lane < M) {
                uint d2 = (uint)(mm >> lane) & 1u;
                vv = d2 ? a + bb : tree[M + lane];
                out[M + lane] = vv;
            }
        }
        if (lane == 0) out[0] = tree[0];
    }
}

extern "C" void kernel_launch(void* const* d_in, const int* in_sizes, int n_in,
                              void* d_out, int out_size, void* d_ws, size_t ws_size,
                              hipStream_t stream) {
    const float* tree    = (const float*)d_in[0];
    const int*   indices = (const int*)d_in[1];
    const float* values  = (const float*)d_in[2];
    float* out = (float*)d_out;

    const int two_cap = in_sizes[0];     // 16,777,216
    const int C       = two_cap >> 1;    // 8,388,608

    uchar* ws = (uchar*)d_ws;
    uint*  fcnt  = (uint*)ws;            // 16 KB
    uchar* l11   = ws + 16384;           // 4 KB
    uint2* fbins = (uint2*)(ws + 32768); // 16 MB

    clear_kernel<<<16, 256, 0, stream>>>(fcnt);
    bin_kernel<<<256, 1024, 0, stream>>>(indices, values, fcnt, fbins);
    merge_kernel<<<C / 2048, 256, 0, stream>>>(tree, fcnt, fbins, l11, out, C);
    tail_kernel<<<1, 1024, 0, stream>>>(tree, l11, out);
}